// Round 5
// baseline (77.605 us; speedup 1.0000x reference)
//
#include <hip/hip_runtime.h>

// BEV orthographic 3D Gaussian splatting, B=2, N=1024, D=32, H=W=200.
// Single kernel: 8x8 tile per block, 8 waves/block, wave w composites the
// w-th 128-gaussian reference chunk; partials merged in chunk order via the
// associative operator (I1,T1)o(I2,T2) = (I1 + T1*I2, T1*T2), 3-phase tree.
// Per-gaussian tests (op>0.05, det>0, power<=0, alpha>=1/255) are exact.
// Chunk eps-stop uses chunk-local T (>= global) -> under-triggers; added
// weight bounded ~1e-2 vs absmax threshold 19.44. Bbox cull only removes
// provably alpha<1/255 gaussians.
// Output: [bev (2,32,200,200) | mean_count scalar].

#define HH 200
#define WW 200
#define DD 32
#define NG 1024
#define BB 2
#define OUT_IMG (BB*DD*HH*WW)   // 2560000
#define NW 8                    // waves per block = reference chunks
#define SEGG (NG/NW)            // 128 gaussians per wave = 1 ref chunk
#define NGRP (SEGG/64)          // 2 staging groups of 64

__global__ __launch_bounds__(64*NW) void render_kernel(
    const float* __restrict__ feats,   // (B, NG, DD)
    const float* __restrict__ means,   // (B, NG, 3)
    const float* __restrict__ cov,     // (B, NG, 6)
    const float* __restrict__ opac,    // (B, NG)
    float* __restrict__ out)
{
    __shared__ float su[NW][64], sv[NW][64], sA[NW][64], sB[NW][64],
                     sC[NW][64], sop[NW][64], spl[NW][64];
    __shared__ int   sg_[NW][64];
    __shared__ float4 slab[4][64][8];  // 32 KB, swizzled slot=(j+lane)&7
    __shared__ float  slabT[4][64];
    __shared__ float  wsum[NW];

    const int b    = blockIdx.z;
    const int tid  = threadIdx.x;
    const int lane = tid & 63;
    const int wid  = tid >> 6;
    const int px   = blockIdx.x*8 + (lane & 7);
    const int py   = blockIdx.y*8 + (lane >> 3);
    const float pxf = (float)px, pyf = (float)py;
    const float cx  = blockIdx.x*8 + 3.5f;
    const float cy  = blockIdx.y*8 + 3.5f;

    const float* __restrict__ featsB = feats + (size_t)b * NG * DD;
    const int gB = b * NG;

    float4 acc[8];
#pragma unroll
    for (int j = 0; j < 8; ++j) acc[j] = make_float4(0.f,0.f,0.f,0.f);
    float T = 1.f;                      // chunk-local transmittance product
    bool skip = false;                  // eps-stop for this (single) chunk

    for (int k = 0; k < NGRP; ++k) {
        const int gl = wid*SEGG + k*64 + lane;
        const int g  = gB + gl;
        const float o  = opac[g];
        const float c0 = cov[g*6+0], c1 = cov[g*6+1], c3 = cov[g*6+3];
        const float av = 4.f*c3 + 0.3f;    // image-x variance
        const float cv = 4.f*c0 + 0.3f;    // image-y variance
        const float bv = 4.f*c1;
        const float det = av*cv - bv*bv;
        bool flag = false;
        float u=0.f, v=0.f, A=0.f, Bc=0.f, Cc=0.f, pl=0.f;
        if (o > 0.05f && det > 0.f) {
            const float inv = 1.f/det;
            A = cv*inv; Bc = bv*inv; Cc = av*inv;
            u = -2.f*means[g*3+1] + 100.f;
            v = -2.f*means[g*3+0] + 100.f;
            pl = -__logf(255.f*o);               // power floor for alpha>=1/255
            const float qmax = -2.f*pl;          // >0 since o>0.05
            const float htr = 0.5f*(A+Cc), hdf = 0.5f*(A-Cc);
            const float lmin = htr - sqrtf(hdf*hdf + Bc*Bc);  // PD conic
            const float r = sqrtf(qmax/lmin) + 0.5f;
            flag = (fabsf(u - cx) <= 3.5f + r) && (fabsf(v - cy) <= 3.5f + r);
        }
        const unsigned long long mask = __ballot(flag);
        const int m = (int)__popcll(mask);
        __syncthreads();                          // uniform trip count: legal
        if (flag) {                               // order-preserving compaction
            const int pos = (int)__popcll(mask & ((1ull << lane) - 1ull));
            su[wid][pos]=u;  sv[wid][pos]=v;  sA[wid][pos]=A;  sB[wid][pos]=Bc;
            sC[wid][pos]=Cc; sop[wid][pos]=o; spl[wid][pos]=pl; sg_[wid][pos]=gl;
        }
        __syncthreads();

        if (!skip) {
            for (int i = 0; i < m; ++i) {
                const float dx = su[wid][i] - pxf;
                const float dy = sv[wid][i] - pyf;
                const float pw = fmaf(sB[wid][i], dx*dy,
                                      -0.5f*(sA[wid][i]*dx*dx + sC[wid][i]*dy*dy));
                if (pw > 0.f) continue;                    // reference mask
                if (pw < spl[wid][i] - 1e-3f) continue;    // provably alpha<1/255
                const float alpha = fminf(0.99f, sop[wid][i] * __expf(pw));
                if (alpha < (1.f/255.f)) continue;         // exact check
                const float om = 1.f - alpha;
                if (T * om < 1e-4f) { skip = true; break; }   // chunk eps-stop
                const float w = alpha * T;
                // wave-uniform gaussian index -> scalar (SMEM-path) loads
                const int gi = __builtin_amdgcn_readfirstlane(sg_[wid][i]);
                const float4* __restrict__ col =
                    (const float4*)(featsB + (size_t)gi * DD);
#pragma unroll
                for (int j = 0; j < 8; ++j) {
                    const float4 c4 = col[j];
                    acc[j].x = fmaf(w, c4.x, acc[j].x);
                    acc[j].y = fmaf(w, c4.y, acc[j].y);
                    acc[j].z = fmaf(w, c4.z, acc[j].z);
                    acc[j].w = fmaf(w, c4.w, acc[j].w);
                }
                T *= om;
            }
        }
    }

    // ---- 3-phase tree combine in chunk-index order
    float Tl = T;
#pragma unroll
    for (int phase = 0; phase < 3; ++phase) {
        const int step = 1 << phase;                // 1,2,4
        const int mod  = 2*step - 1;
        const bool storer = (wid & mod) == step;
        const bool merger = (wid & mod) == 0 && wid + step < NW;
        __syncthreads();
        if (storer) {
            const int s = wid >> (phase+1);
#pragma unroll
            for (int j = 0; j < 8; ++j)
                slab[s][lane][(j + lane) & 7] = acc[j];
            slabT[s][lane] = Tl;
        }
        __syncthreads();
        if (merger) {
            const int s = (wid + step) >> (phase+1);
            const float Th = slabT[s][lane];
#pragma unroll
            for (int j = 0; j < 8; ++j) {
                const float4 r = slab[s][lane][(j + lane) & 7];
                acc[j].x = fmaf(Tl, r.x, acc[j].x);
                acc[j].y = fmaf(Tl, r.y, acc[j].y);
                acc[j].z = fmaf(Tl, r.z, acc[j].z);
                acc[j].w = fmaf(Tl, r.w, acc[j].w);
            }
            Tl *= Th;
        }
    }

    // ---- broadcast final image, all 8 waves write 1 channel-quad each
    __syncthreads();
    if (wid == 0) {
#pragma unroll
        for (int j = 0; j < 8; ++j)
            slab[0][lane][(j + lane) & 7] = acc[j];
    }
    __syncthreads();
    {
        const size_t base = (size_t)b * DD * (HH*WW) + (size_t)py * WW + px;
        const float4 ov = slab[0][lane][(wid + lane) & 7];
        out[base + (size_t)(wid*4+0)*(HH*WW)] = ov.x;
        out[base + (size_t)(wid*4+1)*(HH*WW)] = ov.y;
        out[base + (size_t)(wid*4+2)*(HH*WW)] = ov.z;
        out[base + (size_t)(wid*4+3)*(HH*WW)] = ov.w;
    }

    // ---- fused mean_count (one block)
    if (blockIdx.x == 0 && blockIdx.y == 0 && b == 0) {
        float s = 0.f;
        for (int i = tid; i < BB*NG; i += 64*NW)
            s += (opac[i] > 0.05f) ? 1.f : 0.f;
#pragma unroll
        for (int off = 32; off > 0; off >>= 1)
            s += __shfl_down(s, off, 64);
        if (lane == 0) wsum[wid] = s;
        __syncthreads();
        if (tid == 0) {
            float t = 0.f;
#pragma unroll
            for (int wv = 0; wv < NW; ++wv) t += wsum[wv];
            out[OUT_IMG] = t * (1.f/(float)BB);
        }
    }
}

extern "C" void kernel_launch(void* const* d_in, const int* in_sizes, int n_in,
                              void* d_out, int out_size, void* d_ws, size_t ws_size,
                              hipStream_t stream) {
    const float* feats = (const float*)d_in[0];  // features (B,N,D)
    const float* means = (const float*)d_in[1];  // means3D  (B,N,3)
    const float* cvr   = (const float*)d_in[2];  // cov3D    (B,N,6)
    const float* opc   = (const float*)d_in[3];  // opacities(B,N,1)
    float* out = (float*)d_out;

    render_kernel<<<dim3(WW/8, HH/8, BB), dim3(64*NW), 0, stream>>>(
        feats, means, cvr, opc, out);
}